// Round 1
// baseline (274.760 us; speedup 1.0000x reference)
//
#include <hip/hip_runtime.h>
#include <hip/hip_bf16.h>

// Problem constants
#define L_SEQ   900000          // 3000 words * 300 dims
#define N_WORDS 3000
#define WDIM    300
#define NB      4               // batch
#define NF      300             // total filters (100 per conv)
#define SEG     2048            // positions per block
#define NT      320             // threads per block (>= NF, multiple of 64)

// ---------------------------------------------------------------------------
// init: zero the [4][300] max buffer (ws is poisoned 0xAA before each launch)
// ---------------------------------------------------------------------------
__global__ void init_kernel(float* __restrict__ maxbuf) {
    int i = blockIdx.x * 256 + threadIdx.x;
    if (i < NB * NF) maxbuf[i] = 0.0f;
}

// ---------------------------------------------------------------------------
// fused gather + conv(3 kernel sizes, zero-padded to K=5) + relu + global max
// grid: (ceil(L/SEG), NB), block: NT
// Each thread owns ONE filter; all lanes sweep the same positions -> LDS
// broadcast reads (no bank conflicts). atomicMax via int compare (floats>=0).
// ---------------------------------------------------------------------------
__global__ __launch_bounds__(NT) void conv_max_kernel(
    const int*   __restrict__ x,     // [4,3000]
    const float* __restrict__ emb,   // [VOCAB,300]
    const float* __restrict__ w1, const float* __restrict__ b1,  // [100,3],[100]
    const float* __restrict__ w2, const float* __restrict__ b2,  // [100,4],[100]
    const float* __restrict__ w3, const float* __restrict__ b3,  // [100,5],[100]
    float* __restrict__ maxbuf)      // [4,300]
{
    __shared__ __align__(16) float se[SEG + 8];

    const int b     = blockIdx.y;
    const int start = blockIdx.x * SEG;
    const int tid   = threadIdx.x;

    // ---- stage SEG+4 gathered embedding values into LDS (zero past end) ----
    for (int s = tid; s < SEG + 4; s += NT) {
        int pos = start + s;
        float v = 0.0f;
        if (pos < L_SEQ) {
            int w = pos / WDIM;              // pos < 2^24, magic-mul div
            int d = pos - w * WDIM;
            int idx = x[b * N_WORDS + w];
            v = emb[idx * WDIM + d];
        }
        se[s] = v;
    }

    // ---- per-thread filter weights, zero-padded to 5 taps ----
    float wk0 = 0.f, wk1 = 0.f, wk2 = 0.f, wk3 = 0.f, wk4 = 0.f;
    float bias = 0.f;
    int   K = 5;
    const int f = tid;
    if (f < 100) {
        K = 3;
        wk0 = w1[f*3+0]; wk1 = w1[f*3+1]; wk2 = w1[f*3+2];
        bias = b1[f];
    } else if (f < 200) {
        K = 4; int j = f - 100;
        wk0 = w2[j*4+0]; wk1 = w2[j*4+1]; wk2 = w2[j*4+2]; wk3 = w2[j*4+3];
        bias = b2[j];
    } else if (f < 300) {
        K = 5; int j = f - 200;
        wk0 = w3[j*5+0]; wk1 = w3[j*5+1]; wk2 = w3[j*5+2]; wk3 = w3[j*5+3]; wk4 = w3[j*5+4];
        bias = b3[j];
    }

    __syncthreads();

    if (f >= NF) return;

    const bool lastblk = (start + SEG + 4 > L_SEQ);
    const int  tmax    = L_SEQ - K;          // valid conv position t <= tmax
    float m = 0.0f;                          // relu floor

    if (!lastblk) {
        #pragma unroll 2
        for (int i = 0; i < SEG; i += 4) {
            float4 a = *reinterpret_cast<const float4*>(&se[i]);
            float4 c = *reinterpret_cast<const float4*>(&se[i + 4]);
            float e0=a.x, e1=a.y, e2=a.z, e3=a.w, e4=c.x, e5=c.y, e6=c.z, e7=c.w;
            float y0 = bias, y1 = bias, y2 = bias, y3 = bias;
            y0 = fmaf(wk0, e0, y0); y1 = fmaf(wk0, e1, y1); y2 = fmaf(wk0, e2, y2); y3 = fmaf(wk0, e3, y3);
            y0 = fmaf(wk1, e1, y0); y1 = fmaf(wk1, e2, y1); y2 = fmaf(wk1, e3, y2); y3 = fmaf(wk1, e4, y3);
            y0 = fmaf(wk2, e2, y0); y1 = fmaf(wk2, e3, y1); y2 = fmaf(wk2, e4, y2); y3 = fmaf(wk2, e5, y3);
            y0 = fmaf(wk3, e3, y0); y1 = fmaf(wk3, e4, y1); y2 = fmaf(wk3, e5, y2); y3 = fmaf(wk3, e6, y3);
            y0 = fmaf(wk4, e4, y0); y1 = fmaf(wk4, e5, y1); y2 = fmaf(wk4, e6, y2); y3 = fmaf(wk4, e7, y3);
            m = fmaxf(m, fmaxf(fmaxf(y0, y1), fmaxf(y2, y3)));
        }
    } else {
        for (int i = 0; i < SEG; i += 4) {
            float4 a = *reinterpret_cast<const float4*>(&se[i]);
            float4 c = *reinterpret_cast<const float4*>(&se[i + 4]);
            float e0=a.x, e1=a.y, e2=a.z, e3=a.w, e4=c.x, e5=c.y, e6=c.z, e7=c.w;
            float y0 = bias, y1 = bias, y2 = bias, y3 = bias;
            y0 = fmaf(wk0, e0, y0); y1 = fmaf(wk0, e1, y1); y2 = fmaf(wk0, e2, y2); y3 = fmaf(wk0, e3, y3);
            y0 = fmaf(wk1, e1, y0); y1 = fmaf(wk1, e2, y1); y2 = fmaf(wk1, e3, y2); y3 = fmaf(wk1, e4, y3);
            y0 = fmaf(wk2, e2, y0); y1 = fmaf(wk2, e3, y1); y2 = fmaf(wk2, e4, y2); y3 = fmaf(wk2, e5, y3);
            y0 = fmaf(wk3, e3, y0); y1 = fmaf(wk3, e4, y1); y2 = fmaf(wk3, e5, y2); y3 = fmaf(wk3, e6, y3);
            y0 = fmaf(wk4, e4, y0); y1 = fmaf(wk4, e5, y1); y2 = fmaf(wk4, e6, y2); y3 = fmaf(wk4, e7, y3);
            int t = start + i;
            if (t     <= tmax) m = fmaxf(m, y0);
            if (t + 1 <= tmax) m = fmaxf(m, y1);
            if (t + 2 <= tmax) m = fmaxf(m, y2);
            if (t + 3 <= tmax) m = fmaxf(m, y3);
        }
    }

    // floats are >= 0 here, so int-bit compare == float compare
    atomicMax(reinterpret_cast<int*>(&maxbuf[b * NF + f]), __float_as_int(m));
}

// ---------------------------------------------------------------------------
// FC heads: feats[4,300] @ {34,4,3,44,5}-row heads -> 360 outputs (flat)
// ---------------------------------------------------------------------------
__global__ __launch_bounds__(384) void fc_kernel(
    const float* __restrict__ maxbuf,   // [4,300] = feats
    const float* __restrict__ fw1, const float* __restrict__ fb1,
    const float* __restrict__ fw2, const float* __restrict__ fb2,
    const float* __restrict__ fw3, const float* __restrict__ fb3,
    const float* __restrict__ fw4, const float* __restrict__ fb4,
    const float* __restrict__ fw5, const float* __restrict__ fb5,
    float* __restrict__ out)            // [360]
{
    __shared__ __align__(16) float feats[NB * NF];
    const int tid = threadIdx.x;
    for (int s = tid; s < NB * NF; s += 384) feats[s] = maxbuf[s];
    __syncthreads();

    if (tid >= 360) return;
    const int n = tid;

    const float* Wh; const float* Bh; int dim, off;
    if      (n < 136) { Wh = fw1; Bh = fb1; dim = 34; off = 0;   }
    else if (n < 152) { Wh = fw2; Bh = fb2; dim = 4;  off = 136; }
    else if (n < 164) { Wh = fw3; Bh = fb3; dim = 3;  off = 152; }
    else if (n < 340) { Wh = fw4; Bh = fb4; dim = 44; off = 164; }
    else              { Wh = fw5; Bh = fb5; dim = 5;  off = 340; }

    int r = n - off;
    int b = r / dim;
    int j = r - b * dim;

    float acc = Bh[j];
    const float* wr = Wh + j * WDIM;         // rows are 1200B -> 16B aligned
    const float* fr = &feats[b * WDIM];
    #pragma unroll 5
    for (int k = 0; k < WDIM; k += 4) {
        float4 wv = *reinterpret_cast<const float4*>(wr + k);
        acc = fmaf(wv.x, fr[k+0], acc);
        acc = fmaf(wv.y, fr[k+1], acc);
        acc = fmaf(wv.z, fr[k+2], acc);
        acc = fmaf(wv.w, fr[k+3], acc);
    }
    out[n] = acc;
}

// ---------------------------------------------------------------------------
extern "C" void kernel_launch(void* const* d_in, const int* in_sizes, int n_in,
                              void* d_out, int out_size, void* d_ws, size_t ws_size,
                              hipStream_t stream) {
    const int*   x    = (const int*)  d_in[0];
    const float* emb  = (const float*)d_in[1];
    const float* w1   = (const float*)d_in[2];
    const float* b1   = (const float*)d_in[3];
    const float* w2   = (const float*)d_in[4];
    const float* b2   = (const float*)d_in[5];
    const float* w3   = (const float*)d_in[6];
    const float* b3   = (const float*)d_in[7];
    const float* fw1  = (const float*)d_in[8];
    const float* fb1  = (const float*)d_in[9];
    const float* fw2  = (const float*)d_in[10];
    const float* fb2  = (const float*)d_in[11];
    const float* fw3  = (const float*)d_in[12];
    const float* fb3  = (const float*)d_in[13];
    const float* fw4  = (const float*)d_in[14];
    const float* fb4  = (const float*)d_in[15];
    const float* fw5  = (const float*)d_in[16];
    const float* fb5  = (const float*)d_in[17];
    float* out    = (float*)d_out;
    float* maxbuf = (float*)d_ws;            // [4*300] floats

    init_kernel<<<(NB * NF + 255) / 256, 256, 0, stream>>>(maxbuf);

    dim3 grid((L_SEQ + SEG - 1) / SEG, NB);
    conv_max_kernel<<<grid, NT, 0, stream>>>(x, emb, w1, b1, w2, b2, w3, b3, maxbuf);

    fc_kernel<<<1, 384, 0, stream>>>(maxbuf, fw1, fb1, fw2, fb2, fw3, fb3,
                                     fw4, fb4, fw5, fb5, out);
}